// Round 4
// baseline (275.372 us; speedup 1.0000x reference)
//
#include <hip/hip_runtime.h>

#define ROWS  4
#define BLOCK 256
#define WPB   (BLOCK / 64)   // waves per block

// Empirical occupancy rule on this chip (R1-R3): waves/EU ~= 256/VGPR.
// (256,6) -> vgpr cap ~42 -> 6 waves/EU tier. int32 addressing keeps live set ~37.
__global__ __launch_bounds__(BLOCK, 6)
void encoder_kernel(const int* __restrict__ nodes,
                    const float* __restrict__ W,    // [V,64]
                    const float* __restrict__ L1,   // [B,64]
                    const float* __restrict__ L2,   // [B,64]
                    const float* __restrict__ AW,   // [128]
                    const float* __restrict__ ABv,  // [1]
                    const float* __restrict__ BW,   // [128]
                    const float* __restrict__ BBv,  // [1]
                    const float* __restrict__ GW,   // [64,64] row-major
                    const float* __restrict__ GB,   // [64]
                    float* __restrict__ out,        // [B,64]
                    int nrows)
{
    const int lane = threadIdx.x & 63;
    const int wid  = threadIdx.x >> 6;

    const float aw_s = AW[lane], aw_l = AW[64 + lane];
    const float bw_s = BW[lane], bw_l = BW[64 + lane];
    const float gb   = GB[lane];
    const float ab   = ABv[0],   bb   = BBv[0];

    // per-wave private LDS slice: no block barrier needed anywhere
    __shared__ float c_lds[WPB][ROWS][64];

    const unsigned totalWaves = (unsigned)gridDim.x * WPB;
    const unsigned nGroups    = (unsigned)nrows / ROWS;

    for (unsigned g = (unsigned)blockIdx.x * WPB + wid; g < nGroups; g += totalWaves) {
        const unsigned row0 = g * ROWS;
        const unsigned base = row0 * 64u + (unsigned)lane;   // fits: B*64 = 33.5M < 2^31

        int nidx[ROWS];
#pragma unroll
        for (int r = 0; r < ROWS; ++r) nidx[r] = nodes[row0 + r];

        float sf[ROWS], f1[ROWS], f2[ROWS];
#pragma unroll
        for (int r = 0; r < ROWS; ++r) {
            sf[r] = W[(unsigned)nidx[r] * 64u + (unsigned)lane];  // V*64 = 64M < 2^31
            f1[r] = L1[base + r * 64u];
            f2[r] = L2[base + r * 64u];
        }

        // gates: alpha = dot(self, AW[:64]) + dot(l1, AW[64:]) + ab  (PReLU(a=1) = identity)
#pragma unroll
        for (int r = 0; r < ROWS; ++r) {
            float pa = sf[r] * aw_s + f1[r] * aw_l;
            float pb = sf[r] * bw_s + f2[r] * bw_l;
#pragma unroll
            for (int off = 32; off > 0; off >>= 1) {
                pa += __shfl_xor(pa, off);
                pb += __shfl_xor(pb, off);
            }
            c_lds[wid][r][lane] = sf[r] + (pa + ab) * f1[r] + (pb + bb) * f2[r];
        }
        // wave-internal LDS dependency: compiler inserts lgkmcnt waits; no barrier.

        float acc[ROWS];
#pragma unroll
        for (int r = 0; r < ROWS; ++r) acc[r] = gb;

        // out[d] = sum_k GW[d][k] * c[k]; GW row from L1 (16 KB resident),
        // c broadcast from LDS (same-address b128 reads, conflict-free).
        // unroll 4 bounds transient g4/c4 sets -> keeps reg pressure under the cap
        const float4* gwp = reinterpret_cast<const float4*>(GW + (unsigned)lane * 64u);
#pragma unroll 4
        for (int k4 = 0; k4 < 16; ++k4) {
            const float4 g4 = gwp[k4];
#pragma unroll
            for (int r = 0; r < ROWS; ++r) {
                const float4 c4 = *reinterpret_cast<const float4*>(&c_lds[wid][r][k4 * 4]);
                acc[r] += g4.x * c4.x;
                acc[r] += g4.y * c4.y;
                acc[r] += g4.z * c4.z;
                acc[r] += g4.w * c4.w;
            }
        }

#pragma unroll
        for (int r = 0; r < ROWS; ++r)
            out[base + r * 64u] = acc[r];
    }
}

extern "C" void kernel_launch(void* const* d_in, const int* in_sizes, int n_in,
                              void* d_out, int out_size, void* d_ws, size_t ws_size,
                              hipStream_t stream) {
    const int*   nodes = (const int*)  d_in[0];
    const float* W     = (const float*)d_in[1];
    const float* L1    = (const float*)d_in[2];
    const float* L2    = (const float*)d_in[3];
    const float* AW    = (const float*)d_in[4];
    const float* AB    = (const float*)d_in[5];
    const float* BW    = (const float*)d_in[6];
    const float* BB    = (const float*)d_in[7];
    const float* GW    = (const float*)d_in[8];
    const float* GB    = (const float*)d_in[9];
    float* out = (float*)d_out;
    const int nrows = in_sizes[0];  // B = 524288

    dim3 grid(4096), block(BLOCK);
    hipLaunchKernelGGL(encoder_kernel, grid, block, 0, stream,
                       nodes, W, L1, L2, AW, AB, BW, BB, GW, GB, out, nrows);
}

// Round 5
// 138.732 us; speedup vs baseline: 1.9849x; 1.9849x over previous
//
#include <hip/hip_runtime.h>

typedef __attribute__((ext_vector_type(8))) short short8;   // 8 bf16 in 4 VGPRs
typedef __attribute__((ext_vector_type(4))) float f32x4;    // MFMA accumulator

__device__ inline float dot4(float4 a, float4 b) {
    return a.x * b.x + a.y * b.y + a.z * b.z + a.w * b.w;
}
__device__ inline float4 comb4(float4 s, float a, float4 x, float b, float4 y) {
    return make_float4(s.x + a * x.x + b * y.x,
                       s.y + a * x.y + b * y.y,
                       s.z + a * x.z + b * y.z,
                       s.w + a * x.w + b * y.w);
}
__device__ inline short bf16rne(float x) {   // f32 -> bf16 bits, round-nearest-even
    unsigned u = __float_as_uint(x);
    u += 0x7FFFu + ((u >> 16) & 1u);
    return (short)(u >> 16);
}
__device__ inline short8 pack_bf16(float4 a, float4 b) {
    short8 r;
    r[0] = bf16rne(a.x); r[1] = bf16rne(a.y); r[2] = bf16rne(a.z); r[3] = bf16rne(a.w);
    r[4] = bf16rne(b.x); r[5] = bf16rne(b.y); r[6] = bf16rne(b.z); r[7] = bf16rne(b.w);
    return r;
}

// One wave = one 16-row group. Features loaded directly in MFMA A-fragment
// layout; matvec on the matrix pipe; zero LDS; DS pipe only 4 shuffles.
__global__ __launch_bounds__(256, 2)
void encoder_mfma(const int* __restrict__ nodes,
                  const float* __restrict__ W,    // [V,64]
                  const float* __restrict__ L1,   // [B,64]
                  const float* __restrict__ L2,   // [B,64]
                  const float* __restrict__ AW,   // [128]
                  const float* __restrict__ ABv,  // [1]
                  const float* __restrict__ BW,   // [128]
                  const float* __restrict__ BBv,  // [1]
                  const float* __restrict__ GW,   // [64,64] row-major
                  const float* __restrict__ GB,   // [64]
                  float* __restrict__ out)        // [B,64]
{
    const int lane = threadIdx.x & 63;
    const int wid  = threadIdx.x >> 6;
    const int m    = lane & 15;   // A row / B col / C col within tile
    const int g    = lane >> 4;   // k-group

    const unsigned group = (unsigned)blockIdx.x * 4u + (unsigned)wid;
    const unsigned row0  = group * 16u;
    const unsigned row   = row0 + (unsigned)m;   // the row this lane loads features of

    // float4 indices of this lane's k-chunks: k = 8g..8g+7 and 32+8g..32+8g+7
    const int i0 = 2 * g, i1 = 2 * g + 1, i2 = 8 + 2 * g, i3 = 9 + 2 * g;

    // ---- issue long-latency loads first (gather + streams) ----
    const int nidx = nodes[row];
    const float4* Wp  = reinterpret_cast<const float4*>(W + (unsigned)nidx * 64u);
    const float4* L1p = reinterpret_cast<const float4*>(L1 + row * 64u);
    const float4* L2p = reinterpret_cast<const float4*>(L2 + row * 64u);

    float4 sfa = Wp[i0],  sfb = Wp[i1],  sfc = Wp[i2],  sfd = Wp[i3];
    float4 f1a = L1p[i0], f1b = L1p[i1], f1c = L1p[i2], f1d = L1p[i3];
    float4 f2a = L2p[i0], f2b = L2p[i1], f2c = L2p[i2], f2d = L2p[i3];

    // ---- gates (f32): pa = dot(sf, AW[0:64]) + dot(f1, AW[64:128]) ----
    const float4* AWp = reinterpret_cast<const float4*>(AW);
    const float4* BWp = reinterpret_cast<const float4*>(BW);
    float pa = dot4(sfa, AWp[i0]) + dot4(sfb, AWp[i1])
             + dot4(sfc, AWp[i2]) + dot4(sfd, AWp[i3])
             + dot4(f1a, AWp[16 + i0]) + dot4(f1b, AWp[16 + i1])
             + dot4(f1c, AWp[16 + i2]) + dot4(f1d, AWp[16 + i3]);
    float pb = dot4(sfa, BWp[i0]) + dot4(sfb, BWp[i1])
             + dot4(sfc, BWp[i2]) + dot4(sfd, BWp[i3])
             + dot4(f2a, BWp[16 + i0]) + dot4(f2b, BWp[16 + i1])
             + dot4(f2c, BWp[16 + i2]) + dot4(f2d, BWp[16 + i3]);

    // row m lives on lanes {m, m+16, m+32, m+48}: butterfly over xor 16, 32
    pa += __shfl_xor(pa, 16); pa += __shfl_xor(pa, 32);
    pb += __shfl_xor(pb, 16); pb += __shfl_xor(pb, 32);
    const float alpha = pa + ABv[0];
    const float beta  = pb + BBv[0];

    // ---- combined = sf + alpha*f1 + beta*f2, packed to bf16 A-fragments ----
    const short8 a0 = pack_bf16(comb4(sfa, alpha, f1a, beta, f2a),
                                comb4(sfb, alpha, f1b, beta, f2b));
    const short8 a1 = pack_bf16(comb4(sfc, alpha, f1c, beta, f2c),
                                comb4(sfd, alpha, f1d, beta, f2d));

    // ---- GW^T B-fragments: B[k][n] = GW[n][k]; n = t*16+m, k-chunks as A ----
    // accumulators init to bias: C[m'][n] = GB[n]  (col n = l&15 + 16t, m89 layout)
    f32x4 acc[4];
    short8 b0[4], b1[4];
#pragma unroll
    for (int t = 0; t < 4; ++t) {
        const int n = t * 16 + m;
        const float4* Gp = reinterpret_cast<const float4*>(GW + (unsigned)n * 64u);
        b0[t] = pack_bf16(Gp[i0], Gp[i1]);
        b1[t] = pack_bf16(Gp[i2], Gp[i3]);
        const float gbv = GB[n];
        acc[t][0] = gbv; acc[t][1] = gbv; acc[t][2] = gbv; acc[t][3] = gbv;
    }

#pragma unroll
    for (int t = 0; t < 4; ++t) {
        acc[t] = __builtin_amdgcn_mfma_f32_16x16x32_bf16(a0, b0[t], acc[t], 0, 0, 0);
        acc[t] = __builtin_amdgcn_mfma_f32_16x16x32_bf16(a1, b1[t], acc[t], 0, 0, 0);
    }

    // ---- store: lane holds out[row0 + 4g + r][t*16 + m] ----
#pragma unroll
    for (int t = 0; t < 4; ++t) {
#pragma unroll
        for (int r = 0; r < 4; ++r) {
            out[(row0 + 4u * g + r) * 64u + (unsigned)(t * 16 + m)] = acc[t][r];
        }
    }
}

extern "C" void kernel_launch(void* const* d_in, const int* in_sizes, int n_in,
                              void* d_out, int out_size, void* d_ws, size_t ws_size,
                              hipStream_t stream) {
    const int*   nodes = (const int*)  d_in[0];
    const float* W     = (const float*)d_in[1];
    const float* L1    = (const float*)d_in[2];
    const float* L2    = (const float*)d_in[3];
    const float* AW    = (const float*)d_in[4];
    const float* AB    = (const float*)d_in[5];
    const float* BW    = (const float*)d_in[6];
    const float* BB    = (const float*)d_in[7];
    const float* GW    = (const float*)d_in[8];
    const float* GB    = (const float*)d_in[9];
    float* out = (float*)d_out;
    const int nrows = in_sizes[0];          // B = 524288
    const int groups = nrows / 16;          // 32768
    const int blocks = groups / 4;          // 8192 (4 waves per block)

    hipLaunchKernelGGL(encoder_mfma, dim3(blocks), dim3(256), 0, stream,
                       nodes, W, L1, L2, AW, AB, BW, BB, GW, GB, out);
}

// Round 8
// 137.712 us; speedup vs baseline: 1.9996x; 1.0074x over previous
//
#include <hip/hip_runtime.h>

typedef __attribute__((ext_vector_type(8))) short short8;   // 8 bf16 in 4 VGPRs
typedef __attribute__((ext_vector_type(4))) float f32x4;    // MFMA accumulator

__device__ inline float dot4(float4 a, float4 b) {
    return a.x * b.x + a.y * b.y + a.z * b.z + a.w * b.w;
}
__device__ inline float4 comb4(float4 s, float a, float4 x, float b, float4 y) {
    return make_float4(s.x + a * x.x + b * y.x,
                       s.y + a * x.y + b * y.y,
                       s.z + a * x.z + b * y.z,
                       s.w + a * x.w + b * y.w);
}
__device__ inline short bf16rne(float x) {   // f32 -> bf16 bits, round-nearest-even
    unsigned u = __float_as_uint(x);
    u += 0x7FFFu + ((u >> 16) & 1u);
    return (short)(u >> 16);
}
__device__ inline short8 pack_bf16(float4 a, float4 b) {
    short8 r;
    r[0] = bf16rne(a.x); r[1] = bf16rne(a.y); r[2] = bf16rne(a.z); r[3] = bf16rne(a.w);
    r[4] = bf16rne(b.x); r[5] = bf16rne(b.y); r[6] = bf16rne(b.z); r[7] = bf16rne(b.w);
    return r;
}

// Persistent waves: grid-stride over 16-row groups, nodes index prefetched one
// iteration ahead (breaks the nodes->gather serial chain), GW B-fragments
// packed once per wave. Zero LDS, zero barriers.
__global__ __launch_bounds__(256, 3)   // loose cap (~168): R2/R4 showed spills >> occupancy
void encoder_mfma(const int* __restrict__ nodes,
                  const float* __restrict__ W,    // [V,64]
                  const float* __restrict__ L1,   // [B,64]
                  const float* __restrict__ L2,   // [B,64]
                  const float* __restrict__ AW,   // [128]
                  const float* __restrict__ ABv,  // [1]
                  const float* __restrict__ BW,   // [128]
                  const float* __restrict__ BBv,  // [1]
                  const float* __restrict__ GW,   // [64,64] row-major
                  const float* __restrict__ GB,   // [64]
                  float* __restrict__ out,        // [B,64]
                  int nrows)
{
    const int lane = threadIdx.x & 63;
    const int wid  = threadIdx.x >> 6;
    const int m    = lane & 15;   // A row / C col within tile
    const int g    = lane >> 4;   // k-group

    // float4 indices of this lane's k-chunks: k = 8g..8g+7 and 32+8g..32+8g+7
    const int i0 = 2 * g, i1 = 2 * g + 1, i2 = 8 + 2 * g, i3 = 9 + 2 * g;

    const unsigned nGroups = (unsigned)nrows >> 4;           // 32768
    const unsigned stride  = (unsigned)gridDim.x * 4u;       // total waves = 8192
    unsigned grp = (unsigned)blockIdx.x * 4u + (unsigned)wid;

    // ---- per-wave invariants: GW^T B-fragments (packed, 32 VGPRs) + biases ----
    short8 b0[4], b1[4];
    float  gbv[4];
#pragma unroll
    for (int t = 0; t < 4; ++t) {
        const int n = t * 16 + m;
        const float4* Gp = reinterpret_cast<const float4*>(GW + (unsigned)n * 64u);
        b0[t] = pack_bf16(Gp[i0], Gp[i1]);
        b1[t] = pack_bf16(Gp[i2], Gp[i3]);
        gbv[t] = GB[n];
    }
    const float ab = ABv[0], bb = BBv[0];
    const float4* AWp = reinterpret_cast<const float4*>(AW);
    const float4* BWp = reinterpret_cast<const float4*>(BW);

    // prologue: first group's node index
    int nidx = nodes[grp * 16u + (unsigned)m];

    for (; grp < nGroups; grp += stride) {
        const unsigned row0 = grp * 16u;
        const unsigned row  = row0 + (unsigned)m;

        // ---- issue all 12 feature loads (independent; gather uses prefetched nidx) ----
        const float4* Wp  = reinterpret_cast<const float4*>(W + (unsigned)nidx * 64u);
        const float4* L1p = reinterpret_cast<const float4*>(L1 + row * 64u);
        const float4* L2p = reinterpret_cast<const float4*>(L2 + row * 64u);

        float4 sfa = Wp[i0],  sfb = Wp[i1],  sfc = Wp[i2],  sfd = Wp[i3];
        float4 f1a = L1p[i0], f1b = L1p[i1], f1c = L1p[i2], f1d = L1p[i3];
        float4 f2a = L2p[i0], f2b = L2p[i1], f2c = L2p[i2], f2d = L2p[i3];

        // ---- prefetch next iteration's node index (hides nodes->gather chain) ----
        const unsigned gnext  = grp + stride;
        const unsigned gclamp = (gnext < nGroups) ? gnext : grp;
        const int nidx_next   = nodes[gclamp * 16u + (unsigned)m];

        // ---- gates in f32: pa = dot(sf, AW[:64]) + dot(f1, AW[64:]) ----
        float pa = dot4(sfa, AWp[i0]) + dot4(sfb, AWp[i1])
                 + dot4(sfc, AWp[i2]) + dot4(sfd, AWp[i3])
                 + dot4(f1a, AWp[16 + i0]) + dot4(f1b, AWp[16 + i1])
                 + dot4(f1c, AWp[16 + i2]) + dot4(f1d, AWp[16 + i3]);
        float pb = dot4(sfa, BWp[i0]) + dot4(sfb, BWp[i1])
                 + dot4(sfc, BWp[i2]) + dot4(sfd, BWp[i3])
                 + dot4(f2a, BWp[16 + i0]) + dot4(f2b, BWp[16 + i1])
                 + dot4(f2c, BWp[16 + i2]) + dot4(f2d, BWp[16 + i3]);

        // row m lives on lanes {m, m+16, m+32, m+48}: butterfly over xor 16, 32
        pa += __shfl_xor(pa, 16); pa += __shfl_xor(pa, 32);
        pb += __shfl_xor(pb, 16); pb += __shfl_xor(pb, 32);
        const float alpha = pa + ab;
        const float beta  = pb + bb;

        // ---- combined = sf + alpha*f1 + beta*f2 (f32), pack to bf16 A-fragments ----
        const short8 a0 = pack_bf16(comb4(sfa, alpha, f1a, beta, f2a),
                                    comb4(sfb, alpha, f1b, beta, f2b));
        const short8 a1 = pack_bf16(comb4(sfc, alpha, f1c, beta, f2c),
                                    comb4(sfd, alpha, f1d, beta, f2d));

        // ---- matvec on the matrix pipe: C[m'][n] layout col=lane&15, row=4g+reg ----
        f32x4 acc[4];
#pragma unroll
        for (int t = 0; t < 4; ++t) {
            acc[t][0] = gbv[t]; acc[t][1] = gbv[t]; acc[t][2] = gbv[t]; acc[t][3] = gbv[t];
            acc[t] = __builtin_amdgcn_mfma_f32_16x16x32_bf16(a0, b0[t], acc[t], 0, 0, 0);
            acc[t] = __builtin_amdgcn_mfma_f32_16x16x32_bf16(a1, b1[t], acc[t], 0, 0, 0);
        }

        // ---- store: lane holds out[row0 + 4g + r][t*16 + m] ----
#pragma unroll
        for (int t = 0; t < 4; ++t) {
#pragma unroll
            for (int r = 0; r < 4; ++r) {
                out[(row0 + 4u * (unsigned)g + r) * 64u + (unsigned)(t * 16 + m)] = acc[t][r];
            }
        }

        nidx = nidx_next;
    }
}

extern "C" void kernel_launch(void* const* d_in, const int* in_sizes, int n_in,
                              void* d_out, int out_size, void* d_ws, size_t ws_size,
                              hipStream_t stream) {
    const int*   nodes = (const int*)  d_in[0];
    const float* W     = (const float*)d_in[1];
    const float* L1    = (const float*)d_in[2];
    const float* L2    = (const float*)d_in[3];
    const float* AW    = (const float*)d_in[4];
    const float* AB    = (const float*)d_in[5];
    const float* BW    = (const float*)d_in[6];
    const float* BB    = (const float*)d_in[7];
    const float* GW    = (const float*)d_in[8];
    const float* GB    = (const float*)d_in[9];
    float* out = (float*)d_out;
    const int nrows = in_sizes[0];  // B = 524288

    // 2048 blocks x 4 waves = 8192 persistent waves, 4 groups each (exact division)
    hipLaunchKernelGGL(encoder_mfma, dim3(2048), dim3(256), 0, stream,
                       nodes, W, L1, L2, AW, AB, BW, BB, GW, GB, out, nrows);
}

// Round 9
// 134.187 us; speedup vs baseline: 2.0522x; 1.0263x over previous
//
#include <hip/hip_runtime.h>

typedef __attribute__((ext_vector_type(8))) short short8;   // 8 bf16 in 4 VGPRs
typedef __attribute__((ext_vector_type(4))) float f32x4;    // MFMA accumulator

#define SRF4 17   // LDS row stride in float4 (16 chunks + 1 pad): spreads quad-starts

__device__ inline float dot4(float4 a, float4 b) {
    return a.x * b.x + a.y * b.y + a.z * b.z + a.w * b.w;
}
__device__ inline float4 comb4(float4 s, float a, float4 x, float b, float4 y) {
    return make_float4(s.x + a * x.x + b * y.x,
                       s.y + a * x.y + b * y.y,
                       s.z + a * x.z + b * y.z,
                       s.w + a * x.w + b * y.w);
}
__device__ inline short bf16rne(float x) {   // f32 -> bf16 bits, round-nearest-even
    unsigned u = __float_as_uint(x);
    u += 0x7FFFu + ((u >> 16) & 1u);
    return (short)(u >> 16);
}
__device__ inline short8 pack_bf16(float4 a, float4 b) {
    short8 r;
    r[0] = bf16rne(a.x); r[1] = bf16rne(a.y); r[2] = bf16rne(a.z); r[3] = bf16rne(a.w);
    r[4] = bf16rne(b.x); r[5] = bf16rne(b.y); r[6] = bf16rne(b.z); r[7] = bf16rne(b.w);
    return r;
}

// R8 structure (persistent waves, nodes prefetch, per-wave GW frags, MFMA matvec)
// with ONE change: features are loaded COALESCED (16 lanes per row / contiguous
// blocks, ~8 lines per instruction) and transposed to fragment layout through
// wave-private LDS — replacing R8's 32-line-per-instruction hardware scatters.
__global__ __launch_bounds__(256, 3)
void encoder_mfma(const int* __restrict__ nodes,
                  const float* __restrict__ W,    // [V,64]
                  const float* __restrict__ L1,   // [B,64]
                  const float* __restrict__ L2,   // [B,64]
                  const float* __restrict__ AW,   // [128]
                  const float* __restrict__ ABv,  // [1]
                  const float* __restrict__ BW,   // [128]
                  const float* __restrict__ BBv,  // [1]
                  const float* __restrict__ GW,   // [64,64] row-major
                  const float* __restrict__ GB,   // [64]
                  float* __restrict__ out,        // [B,64]
                  int nrows)
{
    const int lane = threadIdx.x & 63;
    const int wid  = threadIdx.x >> 6;
    const int m    = lane & 15;   // frag row / load chunk index
    const int g    = lane >> 4;   // frag k-group / load row-sub

    // wave-private staging: [wave][array][16 rows x 17 float4]
    __shared__ float4 lds[4][3][16 * SRF4];
    float4* ldsW = lds[wid][0];
    float4* lds1 = lds[wid][1];
    float4* lds2 = lds[wid][2];

    // float4 indices of this lane's k-chunks: k = 8g..8g+7 and 32+8g..32+8g+7
    const int i0 = 2 * g, i1 = 2 * g + 1, i2 = 8 + 2 * g, i3 = 9 + 2 * g;

    const unsigned nGroups = (unsigned)nrows >> 4;           // 32768
    const unsigned stride  = (unsigned)gridDim.x * 4u;       // total waves = 8192
    unsigned grp = (unsigned)blockIdx.x * 4u + (unsigned)wid;

    // ---- per-wave invariants: GW^T B-fragments + biases (amortized) ----
    short8 b0[4], b1[4];
    float  gbv[4];
#pragma unroll
    for (int t = 0; t < 4; ++t) {
        const int n = t * 16 + m;
        const float4* Gp = reinterpret_cast<const float4*>(GW + (unsigned)n * 64u);
        b0[t] = pack_bf16(Gp[i0], Gp[i1]);
        b1[t] = pack_bf16(Gp[i2], Gp[i3]);
        gbv[t] = GB[n];
    }
    const float ab = ABv[0], bb = BBv[0];
    const float4* AWp = reinterpret_cast<const float4*>(AW);
    const float4* BWp = reinterpret_cast<const float4*>(BW);

    // prologue: lane holds node index of row m of its first group
    int nv = nodes[grp * 16u + (unsigned)m];

    for (; grp < nGroups; grp += stride) {
        const unsigned row0 = grp * 16u;

        // ---- coalesced loads: instr j covers rows 4j..4j+3, full 256B rows ----
        float4 wt[4], t1[4], t2[4];
        const float4* L1p = reinterpret_cast<const float4*>(L1 + (size_t)row0 * 64u);
        const float4* L2p = reinterpret_cast<const float4*>(L2 + (size_t)row0 * 64u);
#pragma unroll
        for (int j = 0; j < 4; ++j) {
            const int nj = __shfl(nv, 4 * j + g);   // nodes[row0 + 4j + g]
            wt[j] = *reinterpret_cast<const float4*>(W + (unsigned)nj * 64u + 4u * (unsigned)m);
        }
#pragma unroll
        for (int j = 0; j < 4; ++j) t1[j] = L1p[64 * j + lane];
#pragma unroll
        for (int j = 0; j < 4; ++j) t2[j] = L2p[64 * j + lane];

        // ---- prefetch next group's node indices ----
        const unsigned gnext  = grp + stride;
        const unsigned gclamp = (gnext < nGroups) ? gnext : grp;
        const int nv_next     = nodes[gclamp * 16u + (unsigned)m];

        // ---- stage to LDS: (row, chunk) -> [row*17 + chunk] ----
#pragma unroll
        for (int j = 0; j < 4; ++j) ldsW[(4 * j + g) * SRF4 + m] = wt[j];
#pragma unroll
        for (int j = 0; j < 4; ++j) lds1[(4 * j + g) * SRF4 + m] = t1[j];
#pragma unroll
        for (int j = 0; j < 4; ++j) lds2[(4 * j + g) * SRF4 + m] = t2[j];
        // wave-internal dep: compiler inserts lgkmcnt waits; no barrier.

        // ---- fragment reads: row m, chunks i0,i1,i2,i3 ----
        const int fb = m * SRF4;
        const float4 sfa = ldsW[fb + i0], sfb = ldsW[fb + i1],
                     sfc = ldsW[fb + i2], sfd = ldsW[fb + i3];
        const float4 f1a = lds1[fb + i0], f1b = lds1[fb + i1],
                     f1c = lds1[fb + i2], f1d = lds1[fb + i3];
        const float4 f2a = lds2[fb + i0], f2b = lds2[fb + i1],
                     f2c = lds2[fb + i2], f2d = lds2[fb + i3];

        // ---- gates in f32 (R8 verbatim) ----
        float pa = dot4(sfa, AWp[i0]) + dot4(sfb, AWp[i1])
                 + dot4(sfc, AWp[i2]) + dot4(sfd, AWp[i3])
                 + dot4(f1a, AWp[16 + i0]) + dot4(f1b, AWp[16 + i1])
                 + dot4(f1c, AWp[16 + i2]) + dot4(f1d, AWp[16 + i3]);
        float pb = dot4(sfa, BWp[i0]) + dot4(sfb, BWp[i1])
                 + dot4(sfc, BWp[i2]) + dot4(sfd, BWp[i3])
                 + dot4(f2a, BWp[16 + i0]) + dot4(f2b, BWp[16 + i1])
                 + dot4(f2c, BWp[16 + i2]) + dot4(f2d, BWp[16 + i3]);

        pa += __shfl_xor(pa, 16); pa += __shfl_xor(pa, 32);
        pb += __shfl_xor(pb, 16); pb += __shfl_xor(pb, 32);
        const float alpha = pa + ab;
        const float beta  = pb + bb;

        // ---- combined -> bf16 A-fragments ----
        const short8 a0 = pack_bf16(comb4(sfa, alpha, f1a, beta, f2a),
                                    comb4(sfb, alpha, f1b, beta, f2b));
        const short8 a1 = pack_bf16(comb4(sfc, alpha, f1c, beta, f2c),
                                    comb4(sfd, alpha, f1d, beta, f2d));

        // ---- matvec on matrix pipe: C layout col=lane&15, row=4g+reg ----
        f32x4 acc[4];
#pragma unroll
        for (int t = 0; t < 4; ++t) {
            acc[t][0] = gbv[t]; acc[t][1] = gbv[t]; acc[t][2] = gbv[t]; acc[t][3] = gbv[t];
            acc[t] = __builtin_amdgcn_mfma_f32_16x16x32_bf16(a0, b0[t], acc[t], 0, 0, 0);
            acc[t] = __builtin_amdgcn_mfma_f32_16x16x32_bf16(a1, b1[t], acc[t], 0, 0, 0);
        }

        // ---- store: lane holds out[row0 + 4g + r][t*16 + m] ----
#pragma unroll
        for (int t = 0; t < 4; ++t) {
#pragma unroll
            for (int r = 0; r < 4; ++r) {
                out[(row0 + 4u * (unsigned)g + r) * 64u + (unsigned)(t * 16 + m)] = acc[t][r];
            }
        }

        nv = nv_next;
    }
}

extern "C" void kernel_launch(void* const* d_in, const int* in_sizes, int n_in,
                              void* d_out, int out_size, void* d_ws, size_t ws_size,
                              hipStream_t stream) {
    const int*   nodes = (const int*)  d_in[0];
    const float* W     = (const float*)d_in[1];
    const float* L1    = (const float*)d_in[2];
    const float* L2    = (const float*)d_in[3];
    const float* AW    = (const float*)d_in[4];
    const float* AB    = (const float*)d_in[5];
    const float* BW    = (const float*)d_in[6];
    const float* BB    = (const float*)d_in[7];
    const float* GW    = (const float*)d_in[8];
    const float* GB    = (const float*)d_in[9];
    float* out = (float*)d_out;
    const int nrows = in_sizes[0];  // B = 524288

    // 2048 blocks x 4 waves = 8192 persistent waves, 4 groups each (exact division)
    hipLaunchKernelGGL(encoder_mfma, dim3(2048), dim3(256), 0, stream,
                       nodes, W, L1, L2, AW, AB, BW, BB, GW, GB, out, nrows);
}

// Round 12
// 132.964 us; speedup vs baseline: 2.0710x; 1.0092x over previous
//
#include <hip/hip_runtime.h>

typedef __attribute__((ext_vector_type(8))) short short8;   // 8 bf16 in 4 VGPRs
typedef __attribute__((ext_vector_type(4))) float f32x4;    // MFMA accumulator
typedef __attribute__((ext_vector_type(4))) float f4;       // clang vector float4 (nt-load capable)

__device__ inline float dot4(f4 a, f4 b) { return a.x*b.x + a.y*b.y + a.z*b.z + a.w*b.w; }
__device__ inline f4 comb4(f4 s, float al, f4 x, float be, f4 y) { return s + al*x + be*y; }

__device__ inline short bf16rne(float x) {   // f32 -> bf16 bits, round-nearest-even
    unsigned u = __float_as_uint(x);
    u += 0x7FFFu + ((u >> 16) & 1u);
    return (short)(u >> 16);
}
__device__ inline short8 pack_bf16(f4 a, f4 b) {
    short8 r;
    r[0] = bf16rne(a.x); r[1] = bf16rne(a.y); r[2] = bf16rne(a.z); r[3] = bf16rne(a.w);
    r[4] = bf16rne(b.x); r[5] = bf16rne(b.y); r[6] = bf16rne(b.z); r[7] = bf16rne(b.w);
    return r;
}

struct Feats { f4 w[4]; f4 x[4]; f4 y[4]; };   // self / l1 / l2 fragments (48 VGPRs)

// R8 structure + FULL feature double-buffering: group k+1's 12 loads are issued
// before group k's compute, so compute consumes registers loaded a whole
// iteration ago (load->use distance ~= one compute phase instead of ~0).
// Streams use nontemporal loads; out uses nontemporal stores (kills the
// partial-line write-allocate inflation seen in R8/R9: WRITE 172 vs 131 MB).
// Zero LDS, zero barriers.
__global__ __launch_bounds__(256, 2)   // generous VGPR cap: R2/R4 showed spills >> occupancy
void encoder_mfma(const int* __restrict__ nodes,
                  const float* __restrict__ W,    // [V,64]
                  const float* __restrict__ L1,   // [B,64]
                  const float* __restrict__ L2,   // [B,64]
                  const float* __restrict__ AW,   // [128]
                  const float* __restrict__ ABv,  // [1]
                  const float* __restrict__ BW,   // [128]
                  const float* __restrict__ BBv,  // [1]
                  const float* __restrict__ GW,   // [64,64] row-major
                  const float* __restrict__ GB,   // [64]
                  float* __restrict__ out,        // [B,64]
                  int nrows)
{
    const int lane = threadIdx.x & 63;
    const int wid  = threadIdx.x >> 6;
    const int m    = lane & 15;   // A row / C col within tile
    const int g    = lane >> 4;   // k-group

    // float4 indices of this lane's k-chunks: k = 8g..8g+7 and 32+8g..32+8g+7
    const int i0 = 2 * g, i1 = 2 * g + 1, i2 = 8 + 2 * g, i3 = 9 + 2 * g;

    const unsigned nGroups = (unsigned)nrows >> 4;           // 32768
    const unsigned stride  = (unsigned)gridDim.x * 4u;       // total waves = 8192

    // ---- per-wave invariants: GW^T B-fragments + biases (amortized) ----
    short8 gB0[4], gB1[4];
    float  gbv[4];
#pragma unroll
    for (int t = 0; t < 4; ++t) {
        const int n = t * 16 + m;
        const f4* Gp = reinterpret_cast<const f4*>(GW + (unsigned)n * 64u);
        gB0[t] = pack_bf16(Gp[i0], Gp[i1]);
        gB1[t] = pack_bf16(Gp[i2], Gp[i3]);
        gbv[t] = GB[n];
    }
    const float ab = ABv[0], bb = BBv[0];
    const f4* AWp = reinterpret_cast<const f4*>(AW);
    const f4* BWp = reinterpret_cast<const f4*>(BW);

    auto load_feats = [&](int nidx, unsigned grpL) -> Feats {
        Feats F;
        const unsigned row = grpL * 16u + (unsigned)m;
        const f4* Wp  = reinterpret_cast<const f4*>(W + (unsigned)nidx * 64u);
        const f4* L1p = reinterpret_cast<const f4*>(L1 + (size_t)row * 64u);
        const f4* L2p = reinterpret_cast<const f4*>(L2 + (size_t)row * 64u);
        F.w[0] = Wp[i0]; F.w[1] = Wp[i1]; F.w[2] = Wp[i2]; F.w[3] = Wp[i3];
        F.x[0] = __builtin_nontemporal_load(L1p + i0);
        F.x[1] = __builtin_nontemporal_load(L1p + i1);
        F.x[2] = __builtin_nontemporal_load(L1p + i2);
        F.x[3] = __builtin_nontemporal_load(L1p + i3);
        F.y[0] = __builtin_nontemporal_load(L2p + i0);
        F.y[1] = __builtin_nontemporal_load(L2p + i1);
        F.y[2] = __builtin_nontemporal_load(L2p + i2);
        F.y[3] = __builtin_nontemporal_load(L2p + i3);
        return F;
    };

    auto compute_store = [&](const Feats& F, unsigned grpC) {
        const unsigned row0 = grpC * 16u;
        // gates in f32
        float pa = dot4(F.w[0], AWp[i0]) + dot4(F.w[1], AWp[i1])
                 + dot4(F.w[2], AWp[i2]) + dot4(F.w[3], AWp[i3])
                 + dot4(F.x[0], AWp[16 + i0]) + dot4(F.x[1], AWp[16 + i1])
                 + dot4(F.x[2], AWp[16 + i2]) + dot4(F.x[3], AWp[16 + i3]);
        float pb = dot4(F.w[0], BWp[i0]) + dot4(F.w[1], BWp[i1])
                 + dot4(F.w[2], BWp[i2]) + dot4(F.w[3], BWp[i3])
                 + dot4(F.y[0], BWp[16 + i0]) + dot4(F.y[1], BWp[16 + i1])
                 + dot4(F.y[2], BWp[16 + i2]) + dot4(F.y[3], BWp[16 + i3]);
        // row m lives on lanes {m, m+16, m+32, m+48}
        pa += __shfl_xor(pa, 16); pa += __shfl_xor(pa, 32);
        pb += __shfl_xor(pb, 16); pb += __shfl_xor(pb, 32);
        const float alpha = pa + ab;
        const float beta  = pb + bb;

        const short8 a0 = pack_bf16(comb4(F.w[0], alpha, F.x[0], beta, F.y[0]),
                                    comb4(F.w[1], alpha, F.x[1], beta, F.y[1]));
        const short8 a1 = pack_bf16(comb4(F.w[2], alpha, F.x[2], beta, F.y[2]),
                                    comb4(F.w[3], alpha, F.x[3], beta, F.y[3]));

        f32x4 acc[4];
#pragma unroll
        for (int t = 0; t < 4; ++t) {
            acc[t][0] = gbv[t]; acc[t][1] = gbv[t]; acc[t][2] = gbv[t]; acc[t][3] = gbv[t];
            acc[t] = __builtin_amdgcn_mfma_f32_16x16x32_bf16(a0, gB0[t], acc[t], 0, 0, 0);
            acc[t] = __builtin_amdgcn_mfma_f32_16x16x32_bf16(a1, gB1[t], acc[t], 0, 0, 0);
        }
        // C layout col=lane&15, row=4g+reg (m89-verified); nt stores avoid
        // L2 dirty partial-line write-allocate
#pragma unroll
        for (int t = 0; t < 4; ++t) {
#pragma unroll
            for (int r = 0; r < 4; ++r) {
                __builtin_nontemporal_store(
                    acc[t][r],
                    &out[(row0 + 4u * (unsigned)g + r) * 64u + (unsigned)(t * 16 + m)]);
            }
        }
    };

    // ---- 2-deep pipeline: nodes 2 ahead, features 1 ahead ----
    unsigned grp = (unsigned)blockIdx.x * 4u + (unsigned)wid;
    if (grp >= nGroups) return;

    int nvA = nodes[grp * 16u + (unsigned)m];
    Feats A = load_feats(nvA, grp);
    unsigned gn = grp + stride;
    int nvPF = (gn < nGroups) ? nodes[gn * 16u + (unsigned)m] : 0;

    while (true) {
        // even phase: issue loads for gn (B), compute A@grp
        Feats B;
        const bool hasN = (gn < nGroups);
        if (hasN) {
            B = load_feats(nvPF, gn);
            const unsigned g2 = gn + stride;
            nvA = (g2 < nGroups) ? nodes[g2 * 16u + (unsigned)m] : 0;
        }
        compute_store(A, grp);
        if (!hasN) return;
        grp = gn; gn += stride;

        // odd phase: issue loads for gn (A), compute B@grp
        const bool hasN2 = (gn < nGroups);
        if (hasN2) {
            A = load_feats(nvA, gn);
            const unsigned g2 = gn + stride;
            nvPF = (g2 < nGroups) ? nodes[g2 * 16u + (unsigned)m] : 0;
        }
        compute_store(B, grp);
        if (!hasN2) return;
        grp = gn; gn += stride;
    }
}

extern "C" void kernel_launch(void* const* d_in, const int* in_sizes, int n_in,
                              void* d_out, int out_size, void* d_ws, size_t ws_size,
                              hipStream_t stream) {
    const int*   nodes = (const int*)  d_in[0];
    const float* W     = (const float*)d_in[1];
    const float* L1    = (const float*)d_in[2];
    const float* L2    = (const float*)d_in[3];
    const float* AW    = (const float*)d_in[4];
    const float* AB    = (const float*)d_in[5];
    const float* BW    = (const float*)d_in[6];
    const float* BB    = (const float*)d_in[7];
    const float* GW    = (const float*)d_in[8];
    const float* GB    = (const float*)d_in[9];
    float* out = (float*)d_out;
    const int nrows = in_sizes[0];  // B = 524288

    // 2048 blocks x 4 waves = 8192 persistent waves, 4 groups each (exact division)
    hipLaunchKernelGGL(encoder_mfma, dim3(2048), dim3(256), 0, stream,
                       nodes, W, L1, L2, AW, AB, BW, BB, GW, GB, out, nrows);
}

// Round 13
// 121.851 us; speedup vs baseline: 2.2599x; 1.0912x over previous
//
#include <hip/hip_runtime.h>

typedef __attribute__((ext_vector_type(8))) short short8;   // 8 bf16 in 4 VGPRs
typedef __attribute__((ext_vector_type(4))) float f32x4;    // MFMA accumulator
typedef __attribute__((ext_vector_type(4))) float f4;       // clang vector float4 (nt-load capable)

__device__ inline float dot4(f4 a, f4 b) { return a.x*b.x + a.y*b.y + a.z*b.z + a.w*b.w; }
__device__ inline f4 comb4(f4 s, float al, f4 x, float be, f4 y) { return s + al*x + be*y; }

__device__ inline short bf16rne(float x) {   // f32 -> bf16 bits, round-nearest-even
    unsigned u = __float_as_uint(x);
    u += 0x7FFFu + ((u >> 16) & 1u);
    return (short)(u >> 16);
}
__device__ inline short8 pack_bf16(f4 a, f4 b) {
    short8 r;
    r[0] = bf16rne(a.x); r[1] = bf16rne(a.y); r[2] = bf16rne(a.z); r[3] = bf16rne(a.w);
    r[4] = bf16rne(b.x); r[5] = bf16rne(b.y); r[6] = bf16rne(b.z); r[7] = bf16rne(b.w);
    return r;
}

struct Feats { f4 w[4]; f4 x[4]; f4 y[4]; };   // self / l1 / l2 fragments (48 VGPRs)

// R12 structure with two fixes:
//  (a) plain dword stores (R12's nt-stores inflated WRITE 131->187 MB: no-allocate
//      64B partial-line writes defeat L2 coalescing; R8 proved plain = 131 exact)
//  (b) __launch_bounds__(256,1): R12's (256,2) made the allocator self-cap at
//      VGPR=128 = exactly 2xFeats+GWfrags with ZERO regs left -> pipeline got
//      serialized to fit. Cap 512 lets the 2-deep pipeline + addressing coexist.
// Zero LDS, zero barriers. nt-loads kept (FETCH 277->204 MB win).
__global__ __launch_bounds__(256, 1)
void encoder_mfma(const int* __restrict__ nodes,
                  const float* __restrict__ W,    // [V,64]
                  const float* __restrict__ L1,   // [B,64]
                  const float* __restrict__ L2,   // [B,64]
                  const float* __restrict__ AW,   // [128]
                  const float* __restrict__ ABv,  // [1]
                  const float* __restrict__ BW,   // [128]
                  const float* __restrict__ BBv,  // [1]
                  const float* __restrict__ GW,   // [64,64] row-major
                  const float* __restrict__ GB,   // [64]
                  float* __restrict__ out,        // [B,64]
                  int nrows)
{
    const int lane = threadIdx.x & 63;
    const int wid  = threadIdx.x >> 6;
    const int m    = lane & 15;   // A row / C col within tile
    const int g    = lane >> 4;   // k-group

    // float4 indices of this lane's k-chunks: k = 8g..8g+7 and 32+8g..32+8g+7
    const int i0 = 2 * g, i1 = 2 * g + 1, i2 = 8 + 2 * g, i3 = 9 + 2 * g;

    const unsigned nGroups = (unsigned)nrows >> 4;           // 32768
    const unsigned stride  = (unsigned)gridDim.x * 4u;       // total waves = 8192

    // ---- per-wave invariants: GW^T B-fragments + biases (amortized) ----
    short8 gB0[4], gB1[4];
    float  gbv[4];
#pragma unroll
    for (int t = 0; t < 4; ++t) {
        const int n = t * 16 + m;
        const f4* Gp = reinterpret_cast<const f4*>(GW + (unsigned)n * 64u);
        gB0[t] = pack_bf16(Gp[i0], Gp[i1]);
        gB1[t] = pack_bf16(Gp[i2], Gp[i3]);
        gbv[t] = GB[n];
    }
    const float ab = ABv[0], bb = BBv[0];
    const f4* AWp = reinterpret_cast<const f4*>(AW);
    const f4* BWp = reinterpret_cast<const f4*>(BW);

    auto load_feats = [&](int nidx, unsigned grpL) -> Feats {
        Feats F;
        const unsigned row = grpL * 16u + (unsigned)m;
        const f4* Wp  = reinterpret_cast<const f4*>(W + (unsigned)nidx * 64u);
        const f4* L1p = reinterpret_cast<const f4*>(L1 + (size_t)row * 64u);
        const f4* L2p = reinterpret_cast<const f4*>(L2 + (size_t)row * 64u);
        F.w[0] = Wp[i0]; F.w[1] = Wp[i1]; F.w[2] = Wp[i2]; F.w[3] = Wp[i3];
        F.x[0] = __builtin_nontemporal_load(L1p + i0);
        F.x[1] = __builtin_nontemporal_load(L1p + i1);
        F.x[2] = __builtin_nontemporal_load(L1p + i2);
        F.x[3] = __builtin_nontemporal_load(L1p + i3);
        F.y[0] = __builtin_nontemporal_load(L2p + i0);
        F.y[1] = __builtin_nontemporal_load(L2p + i1);
        F.y[2] = __builtin_nontemporal_load(L2p + i2);
        F.y[3] = __builtin_nontemporal_load(L2p + i3);
        return F;
    };

    auto compute_store = [&](const Feats& F, unsigned grpC) {
        const unsigned row0 = grpC * 16u;
        // gates in f32
        float pa = dot4(F.w[0], AWp[i0]) + dot4(F.w[1], AWp[i1])
                 + dot4(F.w[2], AWp[i2]) + dot4(F.w[3], AWp[i3])
                 + dot4(F.x[0], AWp[16 + i0]) + dot4(F.x[1], AWp[16 + i1])
                 + dot4(F.x[2], AWp[16 + i2]) + dot4(F.x[3], AWp[16 + i3]);
        float pb = dot4(F.w[0], BWp[i0]) + dot4(F.w[1], BWp[i1])
                 + dot4(F.w[2], BWp[i2]) + dot4(F.w[3], BWp[i3])
                 + dot4(F.y[0], BWp[16 + i0]) + dot4(F.y[1], BWp[16 + i1])
                 + dot4(F.y[2], BWp[16 + i2]) + dot4(F.y[3], BWp[16 + i3]);
        // row m lives on lanes {m, m+16, m+32, m+48}
        pa += __shfl_xor(pa, 16); pa += __shfl_xor(pa, 32);
        pb += __shfl_xor(pb, 16); pb += __shfl_xor(pb, 32);
        const float alpha = pa + ab;
        const float beta  = pb + bb;

        const short8 a0 = pack_bf16(comb4(F.w[0], alpha, F.x[0], beta, F.y[0]),
                                    comb4(F.w[1], alpha, F.x[1], beta, F.y[1]));
        const short8 a1 = pack_bf16(comb4(F.w[2], alpha, F.x[2], beta, F.y[2]),
                                    comb4(F.w[3], alpha, F.x[3], beta, F.y[3]));

        f32x4 acc[4];
#pragma unroll
        for (int t = 0; t < 4; ++t) {
            acc[t][0] = gbv[t]; acc[t][1] = gbv[t]; acc[t][2] = gbv[t]; acc[t][3] = gbv[t];
            acc[t] = __builtin_amdgcn_mfma_f32_16x16x32_bf16(a0, gB0[t], acc[t], 0, 0, 0);
            acc[t] = __builtin_amdgcn_mfma_f32_16x16x32_bf16(a1, gB1[t], acc[t], 0, 0, 0);
        }
        // C layout col=lane&15, row=4g+reg (m89-verified); plain stores coalesce
        // to full lines in L2 (R8: WRITE = 131 MB exact)
#pragma unroll
        for (int t = 0; t < 4; ++t) {
#pragma unroll
            for (int r = 0; r < 4; ++r) {
                out[(row0 + 4u * (unsigned)g + r) * 64u + (unsigned)(t * 16 + m)] = acc[t][r];
            }
        }
    };

    // ---- 2-deep pipeline: nodes 2 ahead, features 1 ahead ----
    unsigned grp = (unsigned)blockIdx.x * 4u + (unsigned)wid;
    if (grp >= nGroups) return;

    int nvA = nodes[grp * 16u + (unsigned)m];
    Feats A = load_feats(nvA, grp);
    unsigned gn = grp + stride;
    int nvPF = (gn < nGroups) ? nodes[gn * 16u + (unsigned)m] : 0;

    while (true) {
        // even phase: issue loads for gn (B), compute A@grp
        Feats B;
        const bool hasN = (gn < nGroups);
        if (hasN) {
            B = load_feats(nvPF, gn);
            const unsigned g2 = gn + stride;
            nvA = (g2 < nGroups) ? nodes[g2 * 16u + (unsigned)m] : 0;
        }
        compute_store(A, grp);
        if (!hasN) return;
        grp = gn; gn += stride;

        // odd phase: issue loads for gn (A), compute B@grp
        const bool hasN2 = (gn < nGroups);
        if (hasN2) {
            A = load_feats(nvA, gn);
            const unsigned g2 = gn + stride;
            nvPF = (g2 < nGroups) ? nodes[g2 * 16u + (unsigned)m] : 0;
        }
        compute_store(B, grp);
        if (!hasN2) return;
        grp = gn; gn += stride;
    }
}

extern "C" void kernel_launch(void* const* d_in, const int* in_sizes, int n_in,
                              void* d_out, int out_size, void* d_ws, size_t ws_size,
                              hipStream_t stream) {
    const int*   nodes = (const int*)  d_in[0];
    const float* W     = (const float*)d_in[1];
    const float* L1    = (const float*)d_in[2];
    const float* L2    = (const float*)d_in[3];
    const float* AW    = (const float*)d_in[4];
    const float* AB    = (const float*)d_in[5];
    const float* BW    = (const float*)d_in[6];
    const float* BB    = (const float*)d_in[7];
    const float* GW    = (const float*)d_in[8];
    const float* GB    = (const float*)d_in[9];
    float* out = (float*)d_out;
    const int nrows = in_sizes[0];  // B = 524288

    // 2048 blocks x 4 waves = 8192 persistent waves, 4 groups each (exact division)
    hipLaunchKernelGGL(encoder_mfma, dim3(2048), dim3(256), 0, stream,
                       nodes, W, L1, L2, AW, AB, BW, BB, GW, GB, out, nrows);
}